// Round 11
// baseline (202.257 us; speedup 1.0000x reference)
//
#include <hip/hip_runtime.h>
#include <hip/hip_bf16.h>

#define BATCH     16384
#define INFEAT    4096
#define NCHUNK    8
#define CIN       512
#define COUT      512
#define ACT_GRID  2048
#define OUT_MAIN  (BATCH * 1024)            // 16777216 f32 elements
#define LDA       40

typedef short bf16x8 __attribute__((ext_vector_type(8)));
typedef float f32x4  __attribute__((ext_vector_type(4)));

static __device__ inline unsigned short f2bf_rne(float f) {
    unsigned int u = __builtin_bit_cast(unsigned int, f);
    unsigned int r = (u + 0x7fffu + ((u >> 16) & 1u)) >> 16;
    return (unsigned short)r;
}

// ---------------- K1: per-block partial abs-sums; part is chunk-major [8][2048] ----------------
__global__ __launch_bounds__(256, 4)
void act_partial_kernel(const float* __restrict__ x, float* __restrict__ part) {
    int t = threadIdx.x;
    float acc[4] = {0.f, 0.f, 0.f, 0.f};
    int r0 = blockIdx.x * 8;
    for (int r = 0; r < 8; ++r) {
        const float4* p = reinterpret_cast<const float4*>(x + (size_t)(r0 + r) * INFEAT);
#pragma unroll
        for (int c = 0; c < 4; ++c) {
            float4 v = p[c * 256 + t];
            acc[c] += fabsf(v.x) + fabsf(v.y) + fabsf(v.z) + fabsf(v.w);
        }
    }
#pragma unroll
    for (int c = 0; c < 4; ++c) {
        float v = acc[c];
        v += __shfl_xor(v, 32); v += __shfl_xor(v, 16); v += __shfl_xor(v, 8);
        v += __shfl_xor(v, 4);  v += __shfl_xor(v, 2);  v += __shfl_xor(v, 1);
        acc[c] = v;
    }
    __shared__ float sred[16];
    int wave = t >> 6, lane = t & 63;
    if (lane == 0) {
#pragma unroll
        for (int c = 0; c < 4; ++c) sred[wave * 4 + c] = acc[c];
    }
    __syncthreads();
    if (t < 8) {
        int c = t >> 1, hi = t & 1;
        part[t * ACT_GRID + blockIdx.x] = sred[(2 * hi) * 4 + c] + sred[(2 * hi + 1) * 4 + c];
    }
}

// Redundant per-block topk from part (fixed order -> bit-identical everywhere).
template <typename ShD>
static __device__ inline void topk_preamble(const float* __restrict__ part, int tt,
                                            ShD* sd, double* act8, int* sidx) {
    int ch = tt >> 5, g = tt & 31;
    double a = 0.0;
    for (int j = 0; j < 64; ++j) a += (double)part[ch * ACT_GRID + g + 32 * j];
    sd[tt] = a;
    __syncthreads();
    if (tt < 8) {
        double tot = 0.0;
        for (int j = 0; j < 32; ++j) tot += sd[tt * 32 + j];
        act8[tt] = tot;
    }
    __syncthreads();
    if (tt == 0) {
        int i0 = 0;
        for (int i = 1; i < 8; ++i) if (act8[i] > act8[i0]) i0 = i;
        int i1 = -1;
        for (int i = 0; i < 8; ++i) {
            if (i == i0) continue;
            if (i1 < 0 || act8[i] > act8[i1]) i1 = i;
        }
        sidx[0] = i0; sidx[1] = i1;
    }
    __syncthreads();
}

// ---------------- K2: topk + W transpose/convert ----------------
__global__ void wtrans_topk_kernel(const float* __restrict__ W, const float* __restrict__ part,
                                   float* __restrict__ out, unsigned short* __restrict__ WT) {
    __shared__ union { double sd[256]; float tile[32][33]; } sh;
    __shared__ double act8[8];
    __shared__ int sidx[2];
    int tx = threadIdx.x, ty = threadIdx.y;
    int tt = ty * 32 + tx;

    topk_preamble(part, tt, sh.sd, act8, sidx);

    int c = blockIdx.z;
    int id = sidx[c];
    if (blockIdx.x == 0 && blockIdx.y == 0 && c == 0) {
        if (tt < 8) out[OUT_MAIN + tt] = (float)(act8[tt] / ((double)BATCH * (double)CIN));
        if (tt == 0) {
            out[OUT_MAIN + 8] = (float)sidx[0];
            out[OUT_MAIN + 9] = (float)sidx[1];
        }
    }
    __syncthreads();

    const float* Wp = W + (size_t)id * (CIN * COUT);
    int i0 = blockIdx.x * 32, o0 = blockIdx.y * 32;
#pragma unroll
    for (int r = 0; r < 4; ++r)
        sh.tile[ty + r * 8][tx] = Wp[(size_t)(i0 + ty + r * 8) * COUT + o0 + tx];
    __syncthreads();
    unsigned short* WTp = WT + (size_t)c * (CIN * COUT);
#pragma unroll
    for (int r = 0; r < 4; ++r)
        WTp[(size_t)(o0 + ty + r * 8) * CIN + i0 + tx] = f2bf_rne(sh.tile[tx][ty + r * 8]);
}

// ---------------- K3: topk + GEMM (R4 structure), 128x128, BK=32 ----------------
__global__ __launch_bounds__(256, 2)
void gemm_topk_kernel(const float* __restrict__ x, const unsigned short* __restrict__ WT,
                      const float* __restrict__ bvec, const float* __restrict__ part,
                      float* __restrict__ out) {
    __shared__ union {
        double sd[256];
        struct { unsigned short As[128 * LDA]; unsigned short Bs[128 * LDA]; } g;
    } sh;
    __shared__ double act8[8];
    __shared__ int sidx[2];
    int t = threadIdx.x;

    topk_preamble(part, t, sh.sd, act8, sidx);

    int c = blockIdx.z;
    int idx = sidx[c];
    __syncthreads();

    int brow = blockIdx.x * 128, bn = blockIdx.y * 128;
    int lane = t & 63, wid = t >> 6;
    int wm = wid >> 1, wn = wid & 1;
    int lrow = lane & 15, lgrp = lane >> 4;
    f32x4 acc[4][4] = {};
    const float* xbase = x + (size_t)brow * INFEAT + idx * CIN;
    const unsigned short* wtbase = WT + (size_t)c * (CIN * COUT);
    int sa_m = t >> 3, sa_c = t & 7;
    int sb_n = t >> 1, sb_h = (t & 1) * 16;

    for (int kt = 0; kt < 16; ++kt) {
        int k0 = kt * 32;
        __syncthreads();
#pragma unroll
        for (int r = 0; r < 4; ++r) {
            int m = r * 32 + sa_m;
            float4 v = *reinterpret_cast<const float4*>(xbase + (size_t)m * INFEAT + k0 + sa_c * 4);
            ushort4 sv;
            sv.x = f2bf_rne(v.x); sv.y = f2bf_rne(v.y); sv.z = f2bf_rne(v.z); sv.w = f2bf_rne(v.w);
            *reinterpret_cast<ushort4*>(&sh.g.As[m * LDA + sa_c * 4]) = sv;
        }
        {
            const unsigned short* bsrc = wtbase + (size_t)(bn + sb_n) * CIN + k0 + sb_h;
            uint4 b0 = *reinterpret_cast<const uint4*>(bsrc);
            uint4 b1 = *reinterpret_cast<const uint4*>(bsrc + 8);
            unsigned short* bdst = &sh.g.Bs[sb_n * LDA + sb_h];
            *reinterpret_cast<uint4*>(bdst)     = b0;
            *reinterpret_cast<uint4*>(bdst + 8) = b1;
        }
        __syncthreads();
        bf16x8 af[4], bfr[4];
#pragma unroll
        for (int mi = 0; mi < 4; ++mi)
            af[mi] = *reinterpret_cast<const bf16x8*>(&sh.g.As[(wm * 64 + mi * 16 + lrow) * LDA + lgrp * 8]);
#pragma unroll
        for (int ni = 0; ni < 4; ++ni)
            bfr[ni] = *reinterpret_cast<const bf16x8*>(&sh.g.Bs[(wn * 64 + ni * 16 + lrow) * LDA + lgrp * 8]);
#pragma unroll
        for (int mi = 0; mi < 4; ++mi)
#pragma unroll
            for (int ni = 0; ni < 4; ++ni)
                acc[mi][ni] = __builtin_amdgcn_mfma_f32_16x16x32_bf16(af[mi], bfr[ni], acc[mi][ni], 0, 0, 0);
    }

    float bias[4];
#pragma unroll
    for (int ni = 0; ni < 4; ++ni)
        bias[ni] = bvec[idx * COUT + bn + wn * 64 + ni * 16 + lrow];
#pragma unroll
    for (int mi = 0; mi < 4; ++mi) {
#pragma unroll
        for (int r = 0; r < 4; ++r) {
            int row = brow + wm * 64 + mi * 16 + lgrp * 4 + r;
            float* orow = out + (size_t)row * 1024 + c * 512 + bn + wn * 64;
#pragma unroll
            for (int ni = 0; ni < 4; ++ni)
                orow[ni * 16 + lrow] = acc[mi][ni][r] + bias[ni];
        }
    }
}

extern "C" void kernel_launch(void* const* d_in, const int* in_sizes, int n_in,
                              void* d_out, int out_size, void* d_ws, size_t ws_size,
                              hipStream_t stream) {
    const float* x = (const float*)d_in[0];
    const float* W = (const float*)d_in[1];
    const float* bv = (const float*)d_in[2];
    float* out = (float*)d_out;

    float* part = (float*)d_ws;                                    // 64 KB, chunk-major [8][2048]
    unsigned short* WT = (unsigned short*)((char*)d_ws + 65792);   // 2 MB bf16 n-major

    // DIAGNOSTIC (R11): act x3 and wtrans x3 (both idempotent -> identical output,
    // graph-capture safe). Delta vs R10 = 2*(act + K2); with R8's gemm+gap=28.7 this
    // pins down act, K2, and the per-launch gap simultaneously.
    act_partial_kernel<<<ACT_GRID, 256, 0, stream>>>(x, part);
    act_partial_kernel<<<ACT_GRID, 256, 0, stream>>>(x, part);
    act_partial_kernel<<<ACT_GRID, 256, 0, stream>>>(x, part);
    wtrans_topk_kernel<<<dim3(16, 16, 2), dim3(32, 8), 0, stream>>>(W, part, out, WT);
    wtrans_topk_kernel<<<dim3(16, 16, 2), dim3(32, 8), 0, stream>>>(W, part, out, WT);
    wtrans_topk_kernel<<<dim3(16, 16, 2), dim3(32, 8), 0, stream>>>(W, part, out, WT);
    gemm_topk_kernel<<<dim3(BATCH / 128, COUT / 128, 2), 256, 0, stream>>>(x, WT, bv, part, out);
}

// Round 12
// 103.281 us; speedup vs baseline: 1.9583x; 1.9583x over previous
//
#include <hip/hip_runtime.h>
#include <hip/hip_bf16.h>

#define BATCH     16384
#define INFEAT    4096
#define NCHUNK    8
#define CIN       512
#define COUT      512
#define ACT_GRID  2048
#define OUT_MAIN  (BATCH * 1024)            // 16777216 f32 elements
#define LDA       40

typedef short bf16x8 __attribute__((ext_vector_type(8)));
typedef float f32x4  __attribute__((ext_vector_type(4)));

static __device__ inline unsigned short f2bf_rne(float f) {
    unsigned int u = __builtin_bit_cast(unsigned int, f);
    unsigned int r = (u + 0x7fffu + ((u >> 16) & 1u)) >> 16;
    return (unsigned short)r;
}

// ---------------- K1: fused act-partials (blocks 0..2047) + all-8-chunk W transpose
// (blocks 2048..4095). W transpose needs no topk -> dependency-free fusion. ----------------
__global__ __launch_bounds__(256, 4)
void act_wtrans_kernel(const float* __restrict__ x, const float* __restrict__ W,
                       float* __restrict__ part, unsigned short* __restrict__ WT8) {
    __shared__ union { float sred[16]; float tile[32][33]; } sh;
    int t = threadIdx.x;
    int bid = blockIdx.x;

    if (bid < ACT_GRID) {
        // act partial abs-sums over 8 rows; part chunk-major [8][2048]
        float acc[4] = {0.f, 0.f, 0.f, 0.f};
        int r0 = bid * 8;
        for (int r = 0; r < 8; ++r) {
            const float4* p = reinterpret_cast<const float4*>(x + (size_t)(r0 + r) * INFEAT);
#pragma unroll
            for (int c = 0; c < 4; ++c) {
                float4 v = p[c * 256 + t];
                acc[c] += fabsf(v.x) + fabsf(v.y) + fabsf(v.z) + fabsf(v.w);
            }
        }
#pragma unroll
        for (int c = 0; c < 4; ++c) {
            float v = acc[c];
            v += __shfl_xor(v, 32); v += __shfl_xor(v, 16); v += __shfl_xor(v, 8);
            v += __shfl_xor(v, 4);  v += __shfl_xor(v, 2);  v += __shfl_xor(v, 1);
            acc[c] = v;
        }
        int wave = t >> 6, lane = t & 63;
        if (lane == 0) {
#pragma unroll
            for (int c = 0; c < 4; ++c) sh.sred[wave * 4 + c] = acc[c];
        }
        __syncthreads();
        if (t < 8) {
            int c = t >> 1, hi = t & 1;
            part[t * ACT_GRID + bid] = sh.sred[(2 * hi) * 4 + c] + sh.sred[(2 * hi + 1) * 4 + c];
        }
    } else {
        // transpose+convert one 32x32 tile of one of the 8 W chunks
        int tl = bid - ACT_GRID;          // 0..2047
        int ch = tl >> 8;                 // 0..7
        int tile = tl & 255;              // 0..255
        int i0 = (tile & 15) * 32, o0 = (tile >> 4) * 32;
        int tx = t & 31, ty = t >> 5;     // 32 x 8
        const float* Wp = W + (size_t)ch * (CIN * COUT);
#pragma unroll
        for (int r = 0; r < 4; ++r)
            sh.tile[ty + r * 8][tx] = Wp[(size_t)(i0 + ty + r * 8) * COUT + o0 + tx];
        __syncthreads();
        unsigned short* WTp = WT8 + (size_t)ch * (CIN * COUT);
#pragma unroll
        for (int r = 0; r < 4; ++r)
            WTp[(size_t)(o0 + ty + r * 8) * CIN + i0 + tx] = f2bf_rne(sh.tile[tx][ty + r * 8]);
    }
}

// Redundant per-block topk from part (fixed order -> bit-identical everywhere).
template <typename ShD>
static __device__ inline void topk_preamble(const float* __restrict__ part, int tt,
                                            ShD* sd, double* act8, int* sidx) {
    int ch = tt >> 5, g = tt & 31;
    double a = 0.0;
    for (int j = 0; j < 64; ++j) a += (double)part[ch * ACT_GRID + g + 32 * j];
    sd[tt] = a;
    __syncthreads();
    if (tt < 8) {
        double tot = 0.0;
        for (int j = 0; j < 32; ++j) tot += sd[tt * 32 + j];
        act8[tt] = tot;
    }
    __syncthreads();
    if (tt == 0) {
        int i0 = 0;
        for (int i = 1; i < 8; ++i) if (act8[i] > act8[i0]) i0 = i;
        int i1 = -1;
        for (int i = 0; i < 8; ++i) {
            if (i == i0) continue;
            if (i1 < 0 || act8[i] > act8[i1]) i1 = i;
        }
        sidx[0] = i0; sidx[1] = i1;
    }
    __syncthreads();
}

// ---------------- K2: topk + GEMM (R4 structure), 128x128, BK=32; block(0,0,0) writes
// activities + indices; B panel read from the all-8 WT8 at sidx[c]. ----------------
__global__ __launch_bounds__(256, 2)
void gemm_topk_kernel(const float* __restrict__ x, const unsigned short* __restrict__ WT8,
                      const float* __restrict__ bvec, const float* __restrict__ part,
                      float* __restrict__ out) {
    __shared__ union {
        double sd[256];
        struct { unsigned short As[128 * LDA]; unsigned short Bs[128 * LDA]; } g;
    } sh;
    __shared__ double act8[8];
    __shared__ int sidx[2];
    int t = threadIdx.x;

    topk_preamble(part, t, sh.sd, act8, sidx);

    int c = blockIdx.z;
    int idx = sidx[c];
    if (blockIdx.x == 0 && blockIdx.y == 0 && c == 0) {
        if (t < 8) out[OUT_MAIN + t] = (float)(act8[t] / ((double)BATCH * (double)CIN));
        if (t == 0) {
            out[OUT_MAIN + 8] = (float)sidx[0];
            out[OUT_MAIN + 9] = (float)sidx[1];
        }
    }
    __syncthreads();   // sd reads done before As/Bs reuse

    int brow = blockIdx.x * 128, bn = blockIdx.y * 128;
    int lane = t & 63, wid = t >> 6;
    int wm = wid >> 1, wn = wid & 1;
    int lrow = lane & 15, lgrp = lane >> 4;
    f32x4 acc[4][4] = {};
    const float* xbase = x + (size_t)brow * INFEAT + idx * CIN;
    const unsigned short* wtbase = WT8 + (size_t)idx * (CIN * COUT);
    int sa_m = t >> 3, sa_c = t & 7;
    int sb_n = t >> 1, sb_h = (t & 1) * 16;

    for (int kt = 0; kt < 16; ++kt) {
        int k0 = kt * 32;
        __syncthreads();
#pragma unroll
        for (int r = 0; r < 4; ++r) {
            int m = r * 32 + sa_m;
            float4 v = *reinterpret_cast<const float4*>(xbase + (size_t)m * INFEAT + k0 + sa_c * 4);
            ushort4 sv;
            sv.x = f2bf_rne(v.x); sv.y = f2bf_rne(v.y); sv.z = f2bf_rne(v.z); sv.w = f2bf_rne(v.w);
            *reinterpret_cast<ushort4*>(&sh.g.As[m * LDA + sa_c * 4]) = sv;
        }
        {
            const unsigned short* bsrc = wtbase + (size_t)(bn + sb_n) * CIN + k0 + sb_h;
            uint4 b0 = *reinterpret_cast<const uint4*>(bsrc);
            uint4 b1 = *reinterpret_cast<const uint4*>(bsrc + 8);
            unsigned short* bdst = &sh.g.Bs[sb_n * LDA + sb_h];
            *reinterpret_cast<uint4*>(bdst)     = b0;
            *reinterpret_cast<uint4*>(bdst + 8) = b1;
        }
        __syncthreads();
        bf16x8 af[4], bfr[4];
#pragma unroll
        for (int mi = 0; mi < 4; ++mi)
            af[mi] = *reinterpret_cast<const bf16x8*>(&sh.g.As[(wm * 64 + mi * 16 + lrow) * LDA + lgrp * 8]);
#pragma unroll
        for (int ni = 0; ni < 4; ++ni)
            bfr[ni] = *reinterpret_cast<const bf16x8*>(&sh.g.Bs[(wn * 64 + ni * 16 + lrow) * LDA + lgrp * 8]);
#pragma unroll
        for (int mi = 0; mi < 4; ++mi)
#pragma unroll
            for (int ni = 0; ni < 4; ++ni)
                acc[mi][ni] = __builtin_amdgcn_mfma_f32_16x16x32_bf16(af[mi], bfr[ni], acc[mi][ni], 0, 0, 0);
    }

    float bias[4];
#pragma unroll
    for (int ni = 0; ni < 4; ++ni)
        bias[ni] = bvec[idx * COUT + bn + wn * 64 + ni * 16 + lrow];
#pragma unroll
    for (int mi = 0; mi < 4; ++mi) {
#pragma unroll
        for (int r = 0; r < 4; ++r) {
            int row = brow + wm * 64 + mi * 16 + lgrp * 4 + r;
            float* orow = out + (size_t)row * 1024 + c * 512 + bn + wn * 64;
#pragma unroll
            for (int ni = 0; ni < 4; ++ni)
                orow[ni * 16 + lrow] = acc[mi][ni][r] + bias[ni];
        }
    }
}

extern "C" void kernel_launch(void* const* d_in, const int* in_sizes, int n_in,
                              void* d_out, int out_size, void* d_ws, size_t ws_size,
                              hipStream_t stream) {
    const float* x = (const float*)d_in[0];
    const float* W = (const float*)d_in[1];
    const float* bv = (const float*)d_in[2];
    float* out = (float*)d_out;

    float* part = (float*)d_ws;                                     // 64 KB, chunk-major [8][2048]
    unsigned short* WT8 = (unsigned short*)((char*)d_ws + 65792);   // 4 MB: all 8 chunks, n-major bf16

    act_wtrans_kernel<<<2 * ACT_GRID, 256, 0, stream>>>(x, W, part, WT8);
    gemm_topk_kernel<<<dim3(BATCH / 128, COUT / 128, 2), 256, 0, stream>>>(x, WT8, bv, part, out);
}

// Round 13
// 102.587 us; speedup vs baseline: 1.9716x; 1.0068x over previous
//
#include <hip/hip_runtime.h>
#include <hip/hip_bf16.h>

#define BATCH     16384
#define INFEAT    4096
#define NCHUNK    8
#define CIN       512
#define COUT      512
#define ACT_GRID  2048
#define OUT_MAIN  (BATCH * 1024)            // 16777216 f32 elements
#define LDA       40

typedef short bf16x8 __attribute__((ext_vector_type(8)));
typedef float f32x4  __attribute__((ext_vector_type(4)));

static __device__ inline unsigned short f2bf_rne(float f) {
    unsigned int u = __builtin_bit_cast(unsigned int, f);
    unsigned int r = (u + 0x7fffu + ((u >> 16) & 1u)) >> 16;
    return (unsigned short)r;
}

// ---------------- K1: fused act-partials (blocks 0..2047) + all-8-chunk W transpose
// (blocks 2048..4095). W transpose needs no topk -> dependency-free fusion. ----------------
__global__ __launch_bounds__(256, 4)
void act_wtrans_kernel(const float* __restrict__ x, const float* __restrict__ W,
                       float* __restrict__ part, unsigned short* __restrict__ WT8) {
    __shared__ union { float sred[16]; float tile[32][33]; } sh;
    int t = threadIdx.x;
    int bid = blockIdx.x;

    if (bid < ACT_GRID) {
        float acc[4] = {0.f, 0.f, 0.f, 0.f};
        int r0 = bid * 8;
        for (int r = 0; r < 8; ++r) {
            const float4* p = reinterpret_cast<const float4*>(x + (size_t)(r0 + r) * INFEAT);
#pragma unroll
            for (int c = 0; c < 4; ++c) {
                float4 v = p[c * 256 + t];
                acc[c] += fabsf(v.x) + fabsf(v.y) + fabsf(v.z) + fabsf(v.w);
            }
        }
#pragma unroll
        for (int c = 0; c < 4; ++c) {
            float v = acc[c];
            v += __shfl_xor(v, 32); v += __shfl_xor(v, 16); v += __shfl_xor(v, 8);
            v += __shfl_xor(v, 4);  v += __shfl_xor(v, 2);  v += __shfl_xor(v, 1);
            acc[c] = v;
        }
        int wave = t >> 6, lane = t & 63;
        if (lane == 0) {
#pragma unroll
            for (int c = 0; c < 4; ++c) sh.sred[wave * 4 + c] = acc[c];
        }
        __syncthreads();
        if (t < 8) {
            int c = t >> 1, hi = t & 1;
            part[t * ACT_GRID + bid] = sh.sred[(2 * hi) * 4 + c] + sh.sred[(2 * hi + 1) * 4 + c];
        }
    } else {
        int tl = bid - ACT_GRID;          // 0..2047
        int ch = tl >> 8;                 // 0..7
        int tile = tl & 255;              // 0..255
        int i0 = (tile & 15) * 32, o0 = (tile >> 4) * 32;
        int tx = t & 31, ty = t >> 5;     // 32 x 8
        const float* Wp = W + (size_t)ch * (CIN * COUT);
#pragma unroll
        for (int r = 0; r < 4; ++r)
            sh.tile[ty + r * 8][tx] = Wp[(size_t)(i0 + ty + r * 8) * COUT + o0 + tx];
        __syncthreads();
        unsigned short* WTp = WT8 + (size_t)ch * (CIN * COUT);
#pragma unroll
        for (int r = 0; r < 4; ++r)
            WTp[(size_t)(o0 + ty + r * 8) * CIN + i0 + tx] = f2bf_rne(sh.tile[tx][ty + r * 8]);
    }
}

// Redundant per-block topk from part (fixed order -> bit-identical everywhere).
template <typename ShD>
static __device__ inline void topk_preamble(const float* __restrict__ part, int tt,
                                            ShD* sd, double* act8, int* sidx) {
    int ch = tt >> 5, g = tt & 31;
    double a = 0.0;
    for (int j = 0; j < 64; ++j) a += (double)part[ch * ACT_GRID + g + 32 * j];
    sd[tt] = a;
    __syncthreads();
    if (tt < 8) {
        double tot = 0.0;
        for (int j = 0; j < 32; ++j) tot += sd[tt * 32 + j];
        act8[tt] = tot;
    }
    __syncthreads();
    if (tt == 0) {
        int i0 = 0;
        for (int i = 1; i < 8; ++i) if (act8[i] > act8[i0]) i0 = i;
        int i1 = -1;
        for (int i = 0; i < 8; ++i) {
            if (i == i0) continue;
            if (i1 < 0 || act8[i] > act8[i1]) i1 = i;
        }
        sidx[0] = i0; sidx[1] = i1;
    }
    __syncthreads();
}

// ---------------- K2: topk + GEMM, 128x256 tile (BN widened), BK=32 ----------------
__global__ __launch_bounds__(256, 2)
void gemm_topk_kernel(const float* __restrict__ x, const unsigned short* __restrict__ WT8,
                      const float* __restrict__ bvec, const float* __restrict__ part,
                      float* __restrict__ out) {
    __shared__ union {
        double sd[256];
        struct { unsigned short As[128 * LDA]; unsigned short Bs[256 * LDA]; } g;
    } sh;
    __shared__ double act8[8];
    __shared__ int sidx[2];
    int t = threadIdx.x;

    topk_preamble(part, t, sh.sd, act8, sidx);

    int c = blockIdx.z;
    int idx = sidx[c];
    if (blockIdx.x == 0 && blockIdx.y == 0 && c == 0) {
        if (t < 8) out[OUT_MAIN + t] = (float)(act8[t] / ((double)BATCH * (double)CIN));
        if (t == 0) {
            out[OUT_MAIN + 8] = (float)sidx[0];
            out[OUT_MAIN + 9] = (float)sidx[1];
        }
    }
    __syncthreads();   // sd reads done before As/Bs reuse

    int brow = blockIdx.x * 128, bn = blockIdx.y * 256;
    int lane = t & 63, wid = t >> 6;
    int wm = wid >> 1, wn = wid & 1;          // wave tile: 64 rows x 128 cols
    int lrow = lane & 15, lgrp = lane >> 4;
    f32x4 acc[4][8] = {};
    const float* xbase = x + (size_t)brow * INFEAT + idx * CIN;
    const unsigned short* wtbase = WT8 + (size_t)idx * (CIN * COUT);
    int sa_m = t >> 3, sa_c = t & 7;

    for (int kt = 0; kt < 16; ++kt) {
        int k0 = kt * 32;
        __syncthreads();
        // stage A: 128 x 32 f32 -> bf16 (unchanged)
#pragma unroll
        for (int r = 0; r < 4; ++r) {
            int m = r * 32 + sa_m;
            float4 v = *reinterpret_cast<const float4*>(xbase + (size_t)m * INFEAT + k0 + sa_c * 4);
            ushort4 sv;
            sv.x = f2bf_rne(v.x); sv.y = f2bf_rne(v.y); sv.z = f2bf_rne(v.z); sv.w = f2bf_rne(v.w);
            *reinterpret_cast<ushort4*>(&sh.g.As[m * LDA + sa_c * 4]) = sv;
        }
        // stage B: 256 rows x 32 k, one row per thread (4 x uint4 = 32 shorts)
        {
            const unsigned short* bsrc = wtbase + (size_t)(bn + t) * CIN + k0;
            uint4 b0 = *reinterpret_cast<const uint4*>(bsrc);
            uint4 b1 = *reinterpret_cast<const uint4*>(bsrc + 8);
            uint4 b2 = *reinterpret_cast<const uint4*>(bsrc + 16);
            uint4 b3 = *reinterpret_cast<const uint4*>(bsrc + 24);
            unsigned short* bdst = &sh.g.Bs[t * LDA];
            *reinterpret_cast<uint4*>(bdst)      = b0;
            *reinterpret_cast<uint4*>(bdst + 8)  = b1;
            *reinterpret_cast<uint4*>(bdst + 16) = b2;
            *reinterpret_cast<uint4*>(bdst + 24) = b3;
        }
        __syncthreads();
        bf16x8 af[4], bfr[8];
#pragma unroll
        for (int mi = 0; mi < 4; ++mi)
            af[mi] = *reinterpret_cast<const bf16x8*>(&sh.g.As[(wm * 64 + mi * 16 + lrow) * LDA + lgrp * 8]);
#pragma unroll
        for (int ni = 0; ni < 8; ++ni)
            bfr[ni] = *reinterpret_cast<const bf16x8*>(&sh.g.Bs[(wn * 128 + ni * 16 + lrow) * LDA + lgrp * 8]);
#pragma unroll
        for (int mi = 0; mi < 4; ++mi)
#pragma unroll
            for (int ni = 0; ni < 8; ++ni)
                acc[mi][ni] = __builtin_amdgcn_mfma_f32_16x16x32_bf16(af[mi], bfr[ni], acc[mi][ni], 0, 0, 0);
    }

    float bias[8];
#pragma unroll
    for (int ni = 0; ni < 8; ++ni)
        bias[ni] = bvec[idx * COUT + bn + wn * 128 + ni * 16 + lrow];
#pragma unroll
    for (int mi = 0; mi < 4; ++mi) {
#pragma unroll
        for (int r = 0; r < 4; ++r) {
            int row = brow + wm * 64 + mi * 16 + lgrp * 4 + r;
            float* orow = out + (size_t)row * 1024 + c * 512 + bn + wn * 128;
#pragma unroll
            for (int ni = 0; ni < 8; ++ni)
                orow[ni * 16 + lrow] = acc[mi][ni][r] + bias[ni];
        }
    }
}

extern "C" void kernel_launch(void* const* d_in, const int* in_sizes, int n_in,
                              void* d_out, int out_size, void* d_ws, size_t ws_size,
                              hipStream_t stream) {
    const float* x = (const float*)d_in[0];
    const float* W = (const float*)d_in[1];
    const float* bv = (const float*)d_in[2];
    float* out = (float*)d_out;

    float* part = (float*)d_ws;                                     // 64 KB, chunk-major [8][2048]
    unsigned short* WT8 = (unsigned short*)((char*)d_ws + 65792);   // 4 MB: all 8 chunks, n-major bf16

    act_wtrans_kernel<<<2 * ACT_GRID, 256, 0, stream>>>(x, W, part, WT8);
    gemm_topk_kernel<<<dim3(BATCH / 128, COUT / 256, 2), 256, 0, stream>>>(x, WT8, bv, part, out);
}